// Round 1
// baseline (744.932 us; speedup 1.0000x reference)
//
#include <hip/hip_runtime.h>
#include <math.h>
#include <stddef.h>

// Problem constants
#define BB 2
#define SS 512
#define DD 768
#define HH 12
#define HDIM 64
#define EE 50
#define DE 50
#define F1 128

// ---------------------------------------------------------------------------
// Generic tiled f32 GEMM: Y[m][n] = sum_k X[m][k] * W[n][k] + bias[n]
// BM=BN=64, BK=32, 256 threads, 4x4 micro-tile.
// ---------------------------------------------------------------------------
__global__ __launch_bounds__(256) void k_gemm_bias(
    const float* __restrict__ X, int ldx,
    const float* __restrict__ W,   // [N][K] row-major
    const float* __restrict__ bias,
    float* __restrict__ Y, int ldy,
    int M, int N, int K)
{
  __shared__ float Xs[32][68];
  __shared__ float Ws[32][68];
  int t = threadIdx.x;
  int tx = t & 15, ty = t >> 4;
  int m0 = blockIdx.y * 64, n0 = blockIdx.x * 64;
  float acc[4][4] = {};
  for (int k0 = 0; k0 < K; k0 += 32) {
    // stage 64x32 tiles (2048 floats = 512 float4, 2 per thread)
#pragma unroll
    for (int q = 0; q < 2; ++q) {
      int idx = t + q * 256;
      int r = idx >> 3, c = (idx & 7) << 2;
      float4 v = *(const float4*)(X + (size_t)(m0 + r) * ldx + k0 + c);
      Xs[c + 0][r] = v.x; Xs[c + 1][r] = v.y; Xs[c + 2][r] = v.z; Xs[c + 3][r] = v.w;
      float4 w = *(const float4*)(W + (size_t)(n0 + r) * K + k0 + c);
      Ws[c + 0][r] = w.x; Ws[c + 1][r] = w.y; Ws[c + 2][r] = w.z; Ws[c + 3][r] = w.w;
    }
    __syncthreads();
#pragma unroll
    for (int kk = 0; kk < 32; ++kk) {
      float a[4], b[4];
#pragma unroll
      for (int u = 0; u < 4; ++u) a[u] = Xs[kk][ty * 4 + u];
#pragma unroll
      for (int u = 0; u < 4; ++u) b[u] = Ws[kk][tx * 4 + u];
#pragma unroll
      for (int i = 0; i < 4; ++i)
#pragma unroll
        for (int j = 0; j < 4; ++j) acc[i][j] += a[i] * b[j];
    }
    __syncthreads();
  }
#pragma unroll
  for (int i = 0; i < 4; ++i) {
    int m = m0 + ty * 4 + i;
#pragma unroll
    for (int j = 0; j < 4; ++j) {
      int n = n0 + tx * 4 + j;
      Y[(size_t)m * ldy + n] = acc[i][j] + bias[n];
    }
  }
}

// ---------------------------------------------------------------------------
// attn_src[b,h,s] = sum_hd feature[b,s,h*64+hd]*fc_w1[h,hd]; same for dst/w2
// grid = B*S, 192 threads (12 heads x 16 lanes, float4 per lane)
// ---------------------------------------------------------------------------
__global__ __launch_bounds__(192) void k_attnvec(
    const float* __restrict__ feat, const float* __restrict__ w1,
    const float* __restrict__ w2, float* __restrict__ src, float* __restrict__ dst)
{
  int bs = blockIdx.x;
  int t = threadIdx.x;
  int h = t >> 4, l = t & 15;
  float4 f = *(const float4*)(feat + (size_t)bs * DD + h * HDIM + l * 4);
  float4 a = *(const float4*)(w1 + h * HDIM + l * 4);
  float4 c = *(const float4*)(w2 + h * HDIM + l * 4);
  float ps = f.x * a.x + f.y * a.y + f.z * a.z + f.w * a.w;
  float pd = f.x * c.x + f.y * c.y + f.z * c.z + f.w * c.w;
#pragma unroll
  for (int o = 8; o > 0; o >>= 1) {
    ps += __shfl_xor(ps, o);
    pd += __shfl_xor(pd, o);
  }
  if (l == 0) {
    int b = bs >> 9, s = bs & 511;
    src[((b * HH + h) << 9) + s] = ps;
    dst[((b * HH + h) << 9) + s] = pd;
  }
}

// ---------------------------------------------------------------------------
// Fused edge-MLP -> attention scores (pre-softmax), masked, leaky-relu.
// One block per (b, i, j-chunk of 32). 256 threads.
// scores layout: [b][i][h][j]
// ---------------------------------------------------------------------------
__global__ __launch_bounds__(256) void k_scores(
    const float* __restrict__ wprob, const float* __restrict__ sloop,
    const float* __restrict__ We1, const float* __restrict__ be1,
    const float* __restrict__ We2, const float* __restrict__ be2,
    const float* __restrict__ src, const float* __restrict__ dst,
    float* __restrict__ scores)
{
  __shared__ float We1t[52][132];   // [e][f], rows 50..51 zero
  __shared__ float wpst[52][34];    // [e][jj], rows 50..51 zero
  __shared__ float We2s[12][128];   // [h][f]
  __shared__ float hmids[32][132];  // [jj][f]
  __shared__ float be1s[128];
  __shared__ float be2s[12];
  __shared__ float masks[32];

  int blk = blockIdx.x;
  int c = blk & 15;
  int i = (blk >> 4) & 511;
  int b = blk >> 13;
  int j0 = c << 5;
  int t = threadIdx.x;

  for (int q = t; q < 6400; q += 256) {
    int f = q / 50, e = q % 50;
    We1t[e][f] = We1[q];
  }
  for (int q = t; q < 2 * 132; q += 256) We1t[50 + q / 132][q % 132] = 0.0f;
  for (int q = t; q < 1536; q += 256) We2s[q >> 7][q & 127] = We2[q];
  if (t < 128) be1s[t] = be1[t];
  if (t < 12) be2s[t] = be2[t];
  {
    size_t base = ((size_t)(b * SS + i) * SS + j0) * EE;
    for (int q = t; q < 1600; q += 256) {
      int jj = q / 50, e = q % 50;
      wpst[e][jj] = wprob[base + q] + sloop[base + q];
    }
    for (int q = t; q < 2 * 34; q += 256) wpst[50 + q / 34][q % 34] = 0.0f;
  }
  __syncthreads();

  if (t < 32) {
    float sum = 0.0f;
    for (int e = 0; e < 50; ++e) sum += wpst[e][t];
    masks[t] = (sum == 0.0f) ? 1.0f : 0.0f;
  }

  // hmid = relu(wps @ We1^T + be1): thread -> 2 j x 8 f
  {
    int jj0 = (t & 15) << 1;
    int f0 = (t >> 4) << 3;
    float acc0[8], acc1[8];
#pragma unroll
    for (int u = 0; u < 8; ++u) { acc0[u] = be1s[f0 + u]; acc1[u] = acc0[u]; }
#pragma unroll 4
    for (int e = 0; e < 52; ++e) {
      float a0 = wpst[e][jj0], a1 = wpst[e][jj0 + 1];
#pragma unroll
      for (int u = 0; u < 8; ++u) {
        float w = We1t[e][f0 + u];
        acc0[u] += a0 * w;
        acc1[u] += a1 * w;
      }
    }
#pragma unroll
    for (int u = 0; u < 8; ++u) {
      hmids[jj0][f0 + u] = fmaxf(acc0[u], 0.0f);
      hmids[jj0 + 1][f0 + u] = fmaxf(acc1[u], 0.0f);
    }
  }
  __syncthreads();

  // A[h][jj] = hmid @ We2^T + be2; score = leaky(src+dst+A), mask -> -inf
  for (int o = t; o < 384; o += 256) {
    int jj = o & 31, h = o >> 5;
    float acc = be2s[h];
#pragma unroll 4
    for (int k = 0; k < 128; ++k) acc += hmids[jj][k] * We2s[h][k];
    int j = j0 + jj;
    float sv = src[((b * HH + h) << 9) + i];
    float dv = dst[((b * HH + h) << 9) + j];
    float x = sv + dv + acc;
    x = (x > 0.0f) ? x : 0.01f * x;
    if (masks[jj] != 0.0f) x = -INFINITY;
    scores[(((size_t)(b * SS + i) * HH + h) << 9) + j] = x;
  }
}

// ---------------------------------------------------------------------------
// Softmax over j (per b,i,h) + PV: gcnmid[b,i,:] = sum_j attn * feature[b,j,:]
// One block per 2 rows of i. 256 threads.
// ---------------------------------------------------------------------------
__global__ __launch_bounds__(256) void k_softmax_pv(
    const float* __restrict__ scores, const float* __restrict__ feat,
    float* __restrict__ gout)
{
  __shared__ float p[2][12][512];
  int blk = blockIdx.x;
  int b = blk >> 8;
  int i0 = (blk & 255) << 1;
  int t = threadIdx.x;
  size_t base = ((size_t)(b * SS + i0) * HH) << 9;
  for (int q = t; q < 12288; q += 256) ((float*)p)[q] = scores[base + q];
  __syncthreads();

  int w = t >> 6, l = t & 63;
  for (int r = w; r < 24; r += 4) {
    int ii = r / 12, h = r % 12;
    float* row = p[ii][h];
    float vv[8];
    float m = -INFINITY;
#pragma unroll
    for (int u = 0; u < 8; ++u) {
      vv[u] = row[l + (u << 6)];
      m = fmaxf(m, vv[u]);
    }
#pragma unroll
    for (int o = 32; o > 0; o >>= 1) m = fmaxf(m, __shfl_xor(m, o));
    float s = 0.0f;
#pragma unroll
    for (int u = 0; u < 8; ++u) {
      float e = __expf(vv[u] - m);
      vv[u] = e;
      s += e;
    }
#pragma unroll
    for (int o = 32; o > 0; o >>= 1) s += __shfl_xor(s, o);
    float inv = 1.0f / s;
#pragma unroll
    for (int u = 0; u < 8; ++u) row[l + (u << 6)] = vv[u] * inv;
  }
  __syncthreads();

  float acc[2][3] = {};
  const float* fb = feat + (size_t)b * SS * DD;
  int h0 = t >> 6;
#pragma unroll 4
  for (int j = 0; j < 512; ++j) {
    const float* fr = fb + (size_t)j * DD;
    float f0 = fr[t], f1 = fr[t + 256], f2 = fr[t + 512];
    float p00 = p[0][h0][j], p10 = p[1][h0][j];
    float p01 = p[0][h0 + 4][j], p11 = p[1][h0 + 4][j];
    float p02 = p[0][h0 + 8][j], p12 = p[1][h0 + 8][j];
    acc[0][0] += p00 * f0; acc[0][1] += p01 * f1; acc[0][2] += p02 * f2;
    acc[1][0] += p10 * f0; acc[1][1] += p11 * f1; acc[1][2] += p12 * f2;
  }
#pragma unroll
  for (int ii = 0; ii < 2; ++ii)
#pragma unroll
    for (int u = 0; u < 3; ++u)
      gout[(size_t)(b * SS + i0 + ii) * DD + t + (u << 8)] = acc[ii][u];
}

// ---------------------------------------------------------------------------
// LayerNorm (torch variant: unbiased std, /(std+eps)) + ReLU -> node (d_out)
// ---------------------------------------------------------------------------
__global__ __launch_bounds__(256) void k_ln(
    const float* __restrict__ gcn2, const float* __restrict__ ga,
    const float* __restrict__ gb, float* __restrict__ out)
{
  __shared__ float rs[4], rss[4];
  int row = blockIdx.x;
  int t = threadIdx.x;
  const float* x = gcn2 + (size_t)row * DD;
  float v[3];
  float s = 0.0f, ss2 = 0.0f;
#pragma unroll
  for (int u = 0; u < 3; ++u) {
    v[u] = x[t + (u << 8)];
    s += v[u];
    ss2 += v[u] * v[u];
  }
#pragma unroll
  for (int o = 32; o > 0; o >>= 1) {
    s += __shfl_down(s, o);
    ss2 += __shfl_down(ss2, o);
  }
  int w = t >> 6, l = t & 63;
  if (l == 0) { rs[w] = s; rss[w] = ss2; }
  __syncthreads();
  float S = rs[0] + rs[1] + rs[2] + rs[3];
  float SSum = rss[0] + rss[1] + rss[2] + rss[3];
  float mean = S * (1.0f / 768.0f);
  float var = (SSum - 768.0f * mean * mean) * (1.0f / 767.0f);
  var = fmaxf(var, 0.0f);
  float rinv = 1.0f / (sqrtf(var) + 1e-6f);
#pragma unroll
  for (int u = 0; u < 3; ++u) {
    int cidx = t + (u << 8);
    float y = ga[cidx] * (v[u] - mean) * rinv + gb[cidx];
    out[(size_t)row * DD + cidx] = fmaxf(y, 0.0f);
  }
}

// ---------------------------------------------------------------------------
// P[b,s,f] = ediag[b,s]@Wh_ei^T + node[b,s]@Wh_n2^T
// Q[b,s,f] = ediag[b,s]@Wh_ej^T + node[b,s]@Wh_n1^T + bh
// ---------------------------------------------------------------------------
__global__ __launch_bounds__(256) void k_pq(
    const float* __restrict__ node, const float* __restrict__ wadj,
    const float* __restrict__ Whei, const float* __restrict__ Whej,
    const float* __restrict__ Whn1, const float* __restrict__ Whn2,
    const float* __restrict__ bh, float* __restrict__ P, float* __restrict__ Q)
{
  __shared__ float nd[768];
  __shared__ float ed[50];
  int bs = blockIdx.x;
  int b = bs >> 9, s = bs & 511;
  int t = threadIdx.x;
  for (int q = t; q < 768; q += 256) nd[q] = node[(size_t)bs * DD + q];
  if (t < 50) ed[t] = wadj[((size_t)(b * SS + s) * SS + s) * EE + t];
  __syncthreads();
  int which = t >> 7, f = t & 127;
  if (f < 50) {
    const float* We = which ? Whej : Whei;
    const float* Wn = which ? Whn1 : Whn2;
    float acc = which ? bh[f] : 0.0f;
    for (int e = 0; e < 50; ++e) acc += ed[e] * We[f * EE + e];
    for (int d = 0; d < 768; ++d) acc += nd[d] * Wn[f * DD + d];
    (which ? Q : P)[(size_t)bs * DE + f] = acc;
  }
}

// ---------------------------------------------------------------------------
// edge_out[n,f] = wadj[n,:]@Wh_e[f,:] + P[b,i,f] + Q[b,j,f]
// block = 128 pairs, 256 threads, thread = 4 pairs (stride 32) x 6/7 f
// ---------------------------------------------------------------------------
__global__ __launch_bounds__(256) void k_edge(
    const float* __restrict__ wadj, const float* __restrict__ Whe,
    const float* __restrict__ P, const float* __restrict__ Q,
    float* __restrict__ eout)
{
  __shared__ float adjs[128][51];
  __shared__ float whes[52][52];  // rows 50,51 zero
  int t = threadIdx.x;
  size_t n0 = (size_t)blockIdx.x * 128;
  for (int q = t; q < 2500; q += 256) whes[q / 50][q % 50] = Whe[q];
  for (int q = t; q < 52 * 52 - 2600; q += 256) {
    int qq = q + 2600;  // zero the tail region (covers rows 50,51 and pads)
    whes[qq / 52][qq % 52] = 0.0f;
  }
  // note: row pad columns 50,51 of rows 0..49 may hold garbage; only [e]<50 read
  for (int q = t; q < 6400; q += 256) adjs[q / 50][q % 50] = wadj[n0 * EE + q];
  __syncthreads();

  int pl = t & 31;    // pair lane; pairs pl + 32*pp
  int fg = t >> 5;    // 0..7
  int f0 = fg < 2 ? fg * 7 : 14 + (fg - 2) * 6;
  int nf = fg < 2 ? 7 : 6;
  float acc[4][7] = {};
  for (int e = 0; e < 50; ++e) {
    float aw[7];
#pragma unroll
    for (int u = 0; u < 7; ++u) aw[u] = whes[f0 + u][e];
    float ap0 = adjs[pl][e], ap1 = adjs[pl + 32][e];
    float ap2 = adjs[pl + 64][e], ap3 = adjs[pl + 96][e];
#pragma unroll
    for (int u = 0; u < 7; ++u) {
      acc[0][u] += ap0 * aw[u];
      acc[1][u] += ap1 * aw[u];
      acc[2][u] += ap2 * aw[u];
      acc[3][u] += ap3 * aw[u];
    }
  }
#pragma unroll
  for (int pp = 0; pp < 4; ++pp) {
    size_t n = n0 + pl + 32 * pp;
    int b = (int)(n >> 18);
    int rem = (int)(n & 262143);
    int i = rem >> 9, j = rem & 511;
    const float* Pr = P + (size_t)(b * SS + i) * DE;
    const float* Qr = Q + (size_t)(b * SS + j) * DE;
    float* orow = eout + n * DE;
    for (int u = 0; u < nf; ++u) {
      int f = f0 + u;
      orow[f] = acc[pp][u] + Pr[f] + Qr[f];
    }
  }
}

// ---------------------------------------------------------------------------
extern "C" void kernel_launch(void* const* d_in, const int* in_sizes, int n_in,
                              void* d_out, int out_size, void* d_ws, size_t ws_size,
                              hipStream_t stream)
{
  const float* wprob = (const float*)d_in[0];
  const float* wadj  = (const float*)d_in[1];
  const float* gin   = (const float*)d_in[2];
  const float* sloop = (const float*)d_in[3];
  const float* W_lin = (const float*)d_in[4];
  const float* b_lin = (const float*)d_in[5];
  const float* fw1   = (const float*)d_in[6];
  const float* fw2   = (const float*)d_in[7];
  const float* We1   = (const float*)d_in[8];
  const float* be1   = (const float*)d_in[9];
  const float* We2   = (const float*)d_in[10];
  const float* be2   = (const float*)d_in[11];
  const float* W_out = (const float*)d_in[12];
  const float* b_out = (const float*)d_in[13];
  const float* ln_a  = (const float*)d_in[14];
  const float* ln_b  = (const float*)d_in[15];
  const float* Whe   = (const float*)d_in[16];
  const float* Whei  = (const float*)d_in[17];
  const float* Whej  = (const float*)d_in[18];
  const float* Whn1  = (const float*)d_in[19];
  const float* Whn2  = (const float*)d_in[20];
  const float* bh    = (const float*)d_in[21];

  // workspace layout (floats); requires ws_size >= ~35.2 MB
  float* ws = (float*)d_ws;
  float* feature = ws + 0;         // [B,S,D]      786432
  float* src     = ws + 786432;    // [B,H,S]      12288
  float* dst     = ws + 798720;    // [B,H,S]      12288
  float* scores  = ws + 811008;    // [B,S,H,S]    6291456
  float* gcnmid  = ws + 7102464;   // [B,S,D]      786432
  float* gcn2    = ws + 7888896;   // [B,S,D]      786432
  float* P       = ws + 8675328;   // [B,S,DE]     51200
  float* Q       = ws + 8726528;   // [B,S,DE]     51200

  float* node = (float*)d_out;            // output 0: [B,S,D]
  float* eout = (float*)d_out + 786432;   // output 1: [B,S,S,DE]

  k_gemm_bias<<<dim3(DD / 64, (BB * SS) / 64), 256, 0, stream>>>(
      gin, DD, W_lin, b_lin, feature, DD, BB * SS, DD, DD);
  k_attnvec<<<BB * SS, 192, 0, stream>>>(feature, fw1, fw2, src, dst);
  k_scores<<<BB * SS * (SS / 32), 256, 0, stream>>>(
      wprob, sloop, We1, be1, We2, be2, src, dst, scores);
  k_softmax_pv<<<BB * SS / 2, 256, 0, stream>>>(scores, feature, gcnmid);
  k_gemm_bias<<<dim3(DD / 64, (BB * SS) / 64), 256, 0, stream>>>(
      gcnmid, DD, W_out, b_out, gcn2, DD, BB * SS, DD, DD);
  k_ln<<<BB * SS, 256, 0, stream>>>(gcn2, ln_a, ln_b, node);
  k_pq<<<BB * SS, 256, 0, stream>>>(node, wadj, Whei, Whej, Whn1, Whn2, bh, P, Q);
  k_edge<<<(BB * SS * SS) / 128, 256, 0, stream>>>(wadj, Whe, P, Q, eout);
}

// Round 2
// 579.828 us; speedup vs baseline: 1.2847x; 1.2847x over previous
//
#include <hip/hip_runtime.h>
#include <math.h>
#include <stddef.h>

// Problem constants
#define BB 2
#define SS 512
#define DD 768
#define HH 12
#define HDIM 64
#define EE 50
#define DE 50
#define F1 128

typedef float f32x4 __attribute__((ext_vector_type(4)));
typedef short s16x8 __attribute__((ext_vector_type(8)));

// f32 -> bf16 bits, round-to-nearest-even
static __device__ __forceinline__ unsigned short f2bf(float x) {
  unsigned int u = __float_as_uint(x);
  unsigned int r = u + 0x7fffu + ((u >> 16) & 1u);
  return (unsigned short)(r >> 16);
}
static __device__ __forceinline__ float bf2f(unsigned short b) {
  return __uint_as_float(((unsigned int)b) << 16);
}

// ---------------------------------------------------------------------------
// Generic tiled f32 GEMM: Y[m][n] = sum_k X[m][k] * W[n][k] + bias[n]
// ---------------------------------------------------------------------------
__global__ __launch_bounds__(256) void k_gemm_bias(
    const float* __restrict__ X, int ldx,
    const float* __restrict__ W,   // [N][K] row-major
    const float* __restrict__ bias,
    float* __restrict__ Y, int ldy,
    int M, int N, int K)
{
  __shared__ float Xs[32][68];
  __shared__ float Ws[32][68];
  int t = threadIdx.x;
  int tx = t & 15, ty = t >> 4;
  int m0 = blockIdx.y * 64, n0 = blockIdx.x * 64;
  float acc[4][4] = {};
  for (int k0 = 0; k0 < K; k0 += 32) {
#pragma unroll
    for (int q = 0; q < 2; ++q) {
      int idx = t + q * 256;
      int r = idx >> 3, c = (idx & 7) << 2;
      float4 v = *(const float4*)(X + (size_t)(m0 + r) * ldx + k0 + c);
      Xs[c + 0][r] = v.x; Xs[c + 1][r] = v.y; Xs[c + 2][r] = v.z; Xs[c + 3][r] = v.w;
      float4 w = *(const float4*)(W + (size_t)(n0 + r) * K + k0 + c);
      Ws[c + 0][r] = w.x; Ws[c + 1][r] = w.y; Ws[c + 2][r] = w.z; Ws[c + 3][r] = w.w;
    }
    __syncthreads();
#pragma unroll
    for (int kk = 0; kk < 32; ++kk) {
      float a[4], b[4];
#pragma unroll
      for (int u = 0; u < 4; ++u) a[u] = Xs[kk][ty * 4 + u];
#pragma unroll
      for (int u = 0; u < 4; ++u) b[u] = Ws[kk][tx * 4 + u];
#pragma unroll
      for (int i = 0; i < 4; ++i)
#pragma unroll
        for (int j = 0; j < 4; ++j) acc[i][j] += a[i] * b[j];
    }
    __syncthreads();
  }
#pragma unroll
  for (int i = 0; i < 4; ++i) {
    int m = m0 + ty * 4 + i;
#pragma unroll
    for (int j = 0; j < 4; ++j) {
      int n = n0 + tx * 4 + j;
      Y[(size_t)m * ldy + n] = acc[i][j] + bias[n];
    }
  }
}

// ---------------------------------------------------------------------------
// attn_src[b,h,s], attn_dst[b,h,s]
// ---------------------------------------------------------------------------
__global__ __launch_bounds__(192) void k_attnvec(
    const float* __restrict__ feat, const float* __restrict__ w1,
    const float* __restrict__ w2, float* __restrict__ src, float* __restrict__ dst)
{
  int bs = blockIdx.x;
  int t = threadIdx.x;
  int h = t >> 4, l = t & 15;
  float4 f = *(const float4*)(feat + (size_t)bs * DD + h * HDIM + l * 4);
  float4 a = *(const float4*)(w1 + h * HDIM + l * 4);
  float4 c = *(const float4*)(w2 + h * HDIM + l * 4);
  float ps = f.x * a.x + f.y * a.y + f.z * a.z + f.w * a.w;
  float pd = f.x * c.x + f.y * c.y + f.z * c.z + f.w * c.w;
#pragma unroll
  for (int o = 8; o > 0; o >>= 1) {
    ps += __shfl_xor(ps, o);
    pd += __shfl_xor(pd, o);
  }
  if (l == 0) {
    int b = bs >> 9, s = bs & 511;
    src[((b * HH + h) << 9) + s] = ps;
    dst[((b * HH + h) << 9) + s] = pd;
  }
}

// ---------------------------------------------------------------------------
// MFMA fused edge-MLP -> attention scores (pre-softmax), masked, leaky-relu.
// One block per (b, i, j-tile of 128). 256 threads = 4 waves, wave w owns
// j-rows [w*32, w*32+32).
// Stage A: hmid = relu(wps @ We1^T + be1)   M=128 K=64(pad) N=128  bf16 MFMA
// Stage B: A    = hmid @ We2^T + be2        M=128 K=128 N=16(pad)  bf16 MFMA
// scores layout: [b][i][h][j]
// ---------------------------------------------------------------------------
__global__ __launch_bounds__(256) void k_scores_mfma(
    const float* __restrict__ wprob, const float* __restrict__ sloop,
    const float* __restrict__ We1, const float* __restrict__ be1,
    const float* __restrict__ We2, const float* __restrict__ be2,
    const float* __restrict__ src, const float* __restrict__ dst,
    float* __restrict__ scores)
{
  // strides chosen so 16B ds_read rows are 16B-aligned and 2-way-max on banks
  __shared__ unsigned short wps_s[128][72];    // [j][e]  18432 B (reused as score_s)
  __shared__ unsigned short We1_s[128][72];    // [f][e]  18432 B
  __shared__ unsigned short We2_s[16][136];    // [h][f]   4352 B
  __shared__ unsigned short hmid_s[128][136];  // [j][f]  34816 B
  __shared__ float masks[128];

  int blk = blockIdx.x;
  int jt_tile = blk & 3;
  int i = (blk >> 2) & 511;
  int b = blk >> 11;
  int j0 = jt_tile << 7;
  int t = threadIdx.x;

  // ---- stage weights ----
  for (int q = t; q < 128 * 64; q += 256) {
    int f = q >> 6, e = q & 63;
    We1_s[f][e] = (e < 50) ? f2bf(We1[f * 50 + e]) : (unsigned short)0;
  }
  for (int q = t; q < 16 * 128; q += 256) {
    int h = q >> 7, f = q & 127;
    We2_s[h][f] = (h < 12) ? f2bf(We2[h * 128 + f]) : (unsigned short)0;
  }
  // ---- stage wps = wprob + sloop (f32 -> bf16) ----
  {
    size_t base = ((size_t)((b * SS + i) * SS) + j0) * EE;
    for (int q = t; q < 128 * 64; q += 256) {
      int j = q >> 6, e = q & 63;
      unsigned short v = 0;
      if (e < 50) {
        size_t g = base + (size_t)j * 50 + e;
        v = f2bf(wprob[g] + sloop[g]);
      }
      wps_s[j][e] = v;
    }
  }
  __syncthreads();

  // mask[j] = (sum_e wps == 0); wps >= 0 so bf16 sum==0 iff all zero
  if (t < 128) {
    float s = 0.0f;
    for (int e = 0; e < 50; ++e) s += bf2f(wps_s[t][e]);
    masks[t] = (s == 0.0f) ? 1.0f : 0.0f;
  }

  int w = t >> 6, l = t & 63;
  int lr = l & 15, lg = l >> 4;
  int jbase = w * 32;

  // ---- stage A ----
  f32x4 accA[2][8] = {};
#pragma unroll
  for (int ks = 0; ks < 2; ++ks) {
    s16x8 a0 = *(const s16x8*)&wps_s[jbase + lr][ks * 32 + lg * 8];
    s16x8 a1 = *(const s16x8*)&wps_s[jbase + 16 + lr][ks * 32 + lg * 8];
#pragma unroll
    for (int n = 0; n < 8; ++n) {
      s16x8 bfr = *(const s16x8*)&We1_s[n * 16 + lr][ks * 32 + lg * 8];
      accA[0][n] = __builtin_amdgcn_mfma_f32_16x16x32_bf16(a0, bfr, accA[0][n], 0, 0, 0);
      accA[1][n] = __builtin_amdgcn_mfma_f32_16x16x32_bf16(a1, bfr, accA[1][n], 0, 0, 0);
    }
  }
  // relu(+be1) -> bf16 -> hmid_s (wave-local rows; no block barrier needed)
  {
    float bias[8];
#pragma unroll
    for (int n = 0; n < 8; ++n) bias[n] = be1[n * 16 + lr];
#pragma unroll
    for (int jt = 0; jt < 2; ++jt)
#pragma unroll
      for (int n = 0; n < 8; ++n)
#pragma unroll
        for (int r = 0; r < 4; ++r) {
          float v = fmaxf(accA[jt][n][r] + bias[n], 0.0f);
          hmid_s[jbase + jt * 16 + lg * 4 + r][n * 16 + lr] = f2bf(v);
        }
  }

  // ---- stage B (reads only this wave's hmid rows) ----
  f32x4 accB[2] = {};
#pragma unroll
  for (int kk = 0; kk < 4; ++kk) {
    s16x8 a0 = *(const s16x8*)&hmid_s[jbase + lr][kk * 32 + lg * 8];
    s16x8 a1 = *(const s16x8*)&hmid_s[jbase + 16 + lr][kk * 32 + lg * 8];
    s16x8 bfr = *(const s16x8*)&We2_s[lr][kk * 32 + lg * 8];
    accB[0] = __builtin_amdgcn_mfma_f32_16x16x32_bf16(a0, bfr, accB[0], 0, 0, 0);
    accB[1] = __builtin_amdgcn_mfma_f32_16x16x32_bf16(a1, bfr, accB[1], 0, 0, 0);
  }

  __syncthreads();  // everyone done with wps_s reads -> reuse as score_s
  float* score_s = (float*)wps_s;  // [16][132] padded
  {
    int hh = lr;
    int hc = (hh < 12) ? hh : 11;  // clamp to stay in-bounds; rows 12..15 unused
    float be2v = be2[hc];
    float srcv = src[((b * HH + hc) << 9) + i];
#pragma unroll
    for (int jt = 0; jt < 2; ++jt)
#pragma unroll
      for (int r = 0; r < 4; ++r) {
        int jl = jbase + jt * 16 + lg * 4 + r;
        int j = j0 + jl;
        float dv = dst[((b * HH + hc) << 9) + j];
        float x = accB[jt][r] + be2v + srcv + dv;
        x = (x > 0.0f) ? x : 0.01f * x;
        if (masks[jl] != 0.0f) x = -INFINITY;
        score_s[hh * 132 + jl] = x;
      }
  }
  __syncthreads();
  {
    size_t sbase = ((size_t)(b * SS + i) * HH) << 9;
    for (int q = t; q < 12 * 128; q += 256) {
      int h2 = q >> 7, jj = q & 127;
      scores[sbase + ((size_t)h2 << 9) + j0 + jj] = score_s[h2 * 132 + jj];
    }
  }
}

// ---------------------------------------------------------------------------
// Softmax over j (per b,i,h) + PV: gcnmid[b,i,:] = sum_j attn * feature[b,j,:]
// ---------------------------------------------------------------------------
__global__ __launch_bounds__(256) void k_softmax_pv(
    const float* __restrict__ scores, const float* __restrict__ feat,
    float* __restrict__ gout)
{
  __shared__ float p[2][12][512];
  int blk = blockIdx.x;
  int b = blk >> 8;
  int i0 = (blk & 255) << 1;
  int t = threadIdx.x;
  size_t base = ((size_t)(b * SS + i0) * HH) << 9;
  for (int q = t; q < 12288; q += 256) ((float*)p)[q] = scores[base + q];
  __syncthreads();

  int w = t >> 6, l = t & 63;
  for (int r = w; r < 24; r += 4) {
    int ii = r / 12, h = r % 12;
    float* row = p[ii][h];
    float vv[8];
    float m = -INFINITY;
#pragma unroll
    for (int u = 0; u < 8; ++u) {
      vv[u] = row[l + (u << 6)];
      m = fmaxf(m, vv[u]);
    }
#pragma unroll
    for (int o = 32; o > 0; o >>= 1) m = fmaxf(m, __shfl_xor(m, o));
    float s = 0.0f;
#pragma unroll
    for (int u = 0; u < 8; ++u) {
      float e = __expf(vv[u] - m);
      vv[u] = e;
      s += e;
    }
#pragma unroll
    for (int o = 32; o > 0; o >>= 1) s += __shfl_xor(s, o);
    float inv = 1.0f / s;
#pragma unroll
    for (int u = 0; u < 8; ++u) row[l + (u << 6)] = vv[u] * inv;
  }
  __syncthreads();

  float acc[2][3] = {};
  const float* fb = feat + (size_t)b * SS * DD;
  int h0 = t >> 6;
#pragma unroll 4
  for (int j = 0; j < 512; ++j) {
    const float* fr = fb + (size_t)j * DD;
    float f0 = fr[t], f1 = fr[t + 256], f2 = fr[t + 512];
    float p00 = p[0][h0][j], p10 = p[1][h0][j];
    float p01 = p[0][h0 + 4][j], p11 = p[1][h0 + 4][j];
    float p02 = p[0][h0 + 8][j], p12 = p[1][h0 + 8][j];
    acc[0][0] += p00 * f0; acc[0][1] += p01 * f1; acc[0][2] += p02 * f2;
    acc[1][0] += p10 * f0; acc[1][1] += p11 * f1; acc[1][2] += p12 * f2;
  }
#pragma unroll
  for (int ii = 0; ii < 2; ++ii)
#pragma unroll
    for (int u = 0; u < 3; ++u)
      gout[(size_t)(b * SS + i0 + ii) * DD + t + (u << 8)] = acc[ii][u];
}

// ---------------------------------------------------------------------------
// LayerNorm (torch variant: unbiased std, /(std+eps)) + ReLU -> node (d_out)
// ---------------------------------------------------------------------------
__global__ __launch_bounds__(256) void k_ln(
    const float* __restrict__ gcn2, const float* __restrict__ ga,
    const float* __restrict__ gb, float* __restrict__ out)
{
  __shared__ float rs[4], rss[4];
  int row = blockIdx.x;
  int t = threadIdx.x;
  const float* x = gcn2 + (size_t)row * DD;
  float v[3];
  float s = 0.0f, ss2 = 0.0f;
#pragma unroll
  for (int u = 0; u < 3; ++u) {
    v[u] = x[t + (u << 8)];
    s += v[u];
    ss2 += v[u] * v[u];
  }
#pragma unroll
  for (int o = 32; o > 0; o >>= 1) {
    s += __shfl_down(s, o);
    ss2 += __shfl_down(ss2, o);
  }
  int w = t >> 6, l = t & 63;
  if (l == 0) { rs[w] = s; rss[w] = ss2; }
  __syncthreads();
  float S = rs[0] + rs[1] + rs[2] + rs[3];
  float SSum = rss[0] + rss[1] + rss[2] + rss[3];
  float mean = S * (1.0f / 768.0f);
  float var = (SSum - 768.0f * mean * mean) * (1.0f / 767.0f);
  var = fmaxf(var, 0.0f);
  float rinv = 1.0f / (sqrtf(var) + 1e-6f);
#pragma unroll
  for (int u = 0; u < 3; ++u) {
    int cidx = t + (u << 8);
    float y = ga[cidx] * (v[u] - mean) * rinv + gb[cidx];
    out[(size_t)row * DD + cidx] = fmaxf(y, 0.0f);
  }
}

// ---------------------------------------------------------------------------
// P[b,s,f] = ediag[b,s]@Wh_ei^T + node[b,s]@Wh_n2^T
// Q[b,s,f] = ediag[b,s]@Wh_ej^T + node[b,s]@Wh_n1^T + bh
// ---------------------------------------------------------------------------
__global__ __launch_bounds__(256) void k_pq(
    const float* __restrict__ node, const float* __restrict__ wadj,
    const float* __restrict__ Whei, const float* __restrict__ Whej,
    const float* __restrict__ Whn1, const float* __restrict__ Whn2,
    const float* __restrict__ bh, float* __restrict__ P, float* __restrict__ Q)
{
  __shared__ float nd[768];
  __shared__ float ed[50];
  int bs = blockIdx.x;
  int b = bs >> 9, s = bs & 511;
  int t = threadIdx.x;
  for (int q = t; q < 768; q += 256) nd[q] = node[(size_t)bs * DD + q];
  if (t < 50) ed[t] = wadj[((size_t)(b * SS + s) * SS + s) * EE + t];
  __syncthreads();
  int which = t >> 7, f = t & 127;
  if (f < 50) {
    const float* We = which ? Whej : Whei;
    const float* Wn = which ? Whn1 : Whn2;
    float acc = which ? bh[f] : 0.0f;
    for (int e = 0; e < 50; ++e) acc += ed[e] * We[f * EE + e];
    for (int d = 0; d < 768; ++d) acc += nd[d] * Wn[f * DD + d];
    (which ? Q : P)[(size_t)bs * DE + f] = acc;
  }
}

// ---------------------------------------------------------------------------
// edge_out[n,f] = wadj[n,:]@Wh_e[f,:] + P[b,i,f] + Q[b,j,f]
// ---------------------------------------------------------------------------
__global__ __launch_bounds__(256) void k_edge(
    const float* __restrict__ wadj, const float* __restrict__ Whe,
    const float* __restrict__ P, const float* __restrict__ Q,
    float* __restrict__ eout)
{
  __shared__ float adjs[128][51];
  __shared__ float whes[52][52];
  int t = threadIdx.x;
  size_t n0 = (size_t)blockIdx.x * 128;
  for (int q = t; q < 2500; q += 256) whes[q / 50][q % 50] = Whe[q];
  for (int q = t; q < 52 * 52 - 2600; q += 256) {
    int qq = q + 2600;
    whes[qq / 52][qq % 52] = 0.0f;
  }
  for (int q = t; q < 6400; q += 256) adjs[q / 50][q % 50] = wadj[n0 * EE + q];
  __syncthreads();

  int pl = t & 31;
  int fg = t >> 5;
  int f0 = fg < 2 ? fg * 7 : 14 + (fg - 2) * 6;
  int nf = fg < 2 ? 7 : 6;
  float acc[4][7] = {};
  for (int e = 0; e < 50; ++e) {
    float aw[7];
#pragma unroll
    for (int u = 0; u < 7; ++u) aw[u] = whes[f0 + u][e];
    float ap0 = adjs[pl][e], ap1 = adjs[pl + 32][e];
    float ap2 = adjs[pl + 64][e], ap3 = adjs[pl + 96][e];
#pragma unroll
    for (int u = 0; u < 7; ++u) {
      acc[0][u] += ap0 * aw[u];
      acc[1][u] += ap1 * aw[u];
      acc[2][u] += ap2 * aw[u];
      acc[3][u] += ap3 * aw[u];
    }
  }
#pragma unroll
  for (int pp = 0; pp < 4; ++pp) {
    size_t n = n0 + pl + 32 * pp;
    int b = (int)(n >> 18);
    int rem = (int)(n & 262143);
    int i = rem >> 9, j = rem & 511;
    const float* Pr = P + (size_t)(b * SS + i) * DE;
    const float* Qr = Q + (size_t)(b * SS + j) * DE;
    float* orow = eout + n * DE;
    for (int u = 0; u < nf; ++u) {
      int f = f0 + u;
      orow[f] = acc[pp][u] + Pr[f] + Qr[f];
    }
  }
}

// ---------------------------------------------------------------------------
extern "C" void kernel_launch(void* const* d_in, const int* in_sizes, int n_in,
                              void* d_out, int out_size, void* d_ws, size_t ws_size,
                              hipStream_t stream)
{
  const float* wprob = (const float*)d_in[0];
  const float* wadj  = (const float*)d_in[1];
  const float* gin   = (const float*)d_in[2];
  const float* sloop = (const float*)d_in[3];
  const float* W_lin = (const float*)d_in[4];
  const float* b_lin = (const float*)d_in[5];
  const float* fw1   = (const float*)d_in[6];
  const float* fw2   = (const float*)d_in[7];
  const float* We1   = (const float*)d_in[8];
  const float* be1   = (const float*)d_in[9];
  const float* We2   = (const float*)d_in[10];
  const float* be2   = (const float*)d_in[11];
  const float* W_out = (const float*)d_in[12];
  const float* b_out = (const float*)d_in[13];
  const float* ln_a  = (const float*)d_in[14];
  const float* ln_b  = (const float*)d_in[15];
  const float* Whe   = (const float*)d_in[16];
  const float* Whei  = (const float*)d_in[17];
  const float* Whej  = (const float*)d_in[18];
  const float* Whn1  = (const float*)d_in[19];
  const float* Whn2  = (const float*)d_in[20];
  const float* bh    = (const float*)d_in[21];

  float* ws = (float*)d_ws;
  float* feature = ws + 0;         // [B,S,D]      786432
  float* src     = ws + 786432;    // [B,H,S]      12288
  float* dst     = ws + 798720;    // [B,H,S]      12288
  float* scores  = ws + 811008;    // [B,S,H,S]    6291456
  float* gcnmid  = ws + 7102464;   // [B,S,D]      786432
  float* gcn2    = ws + 7888896;   // [B,S,D]      786432
  float* P       = ws + 8675328;   // [B,S,DE]     51200
  float* Q       = ws + 8726528;   // [B,S,DE]     51200

  float* node = (float*)d_out;            // output 0: [B,S,D]
  float* eout = (float*)d_out + 786432;   // output 1: [B,S,S,DE]

  k_gemm_bias<<<dim3(DD / 64, (BB * SS) / 64), 256, 0, stream>>>(
      gin, DD, W_lin, b_lin, feature, DD, BB * SS, DD, DD);
  k_attnvec<<<BB * SS, 192, 0, stream>>>(feature, fw1, fw2, src, dst);
  k_scores_mfma<<<BB * SS * (SS / 128), 256, 0, stream>>>(
      wprob, sloop, We1, be1, We2, be2, src, dst, scores);
  k_softmax_pv<<<BB * SS / 2, 256, 0, stream>>>(scores, feature, gcnmid);
  k_gemm_bias<<<dim3(DD / 64, (BB * SS) / 64), 256, 0, stream>>>(
      gcnmid, DD, W_out, b_out, gcn2, DD, BB * SS, DD, DD);
  k_ln<<<BB * SS, 256, 0, stream>>>(gcn2, ln_a, ln_b, node);
  k_pq<<<BB * SS, 256, 0, stream>>>(node, wadj, Whei, Whej, Whn1, Whn2, bh, P, Q);
  k_edge<<<(BB * SS * SS) / 128, 256, 0, stream>>>(wadj, Whe, P, Q, eout);
}

// Round 3
// 456.336 us; speedup vs baseline: 1.6324x; 1.2706x over previous
//
#include <hip/hip_runtime.h>
#include <math.h>
#include <stddef.h>

// Problem constants
#define BB 2
#define SS 512
#define DD 768
#define HH 12
#define HDIM 64
#define EE 50
#define DE 50
#define F1 128

typedef float f32x4 __attribute__((ext_vector_type(4)));
typedef short s16x8 __attribute__((ext_vector_type(8)));

// f32 -> bf16 bits, round-to-nearest-even
static __device__ __forceinline__ unsigned short f2bf(float x) {
  unsigned int u = __float_as_uint(x);
  unsigned int r = u + 0x7fffu + ((u >> 16) & 1u);
  return (unsigned short)(r >> 16);
}
static __device__ __forceinline__ float bf2f(unsigned short b) {
  return __uint_as_float(((unsigned int)b) << 16);
}

// ---------------------------------------------------------------------------
// Generic tiled f32 GEMM: Y[m][n] = sum_k X[m][k] * W[n][k] + bias[n]
// ---------------------------------------------------------------------------
__global__ __launch_bounds__(256) void k_gemm_bias(
    const float* __restrict__ X, int ldx,
    const float* __restrict__ W,   // [N][K] row-major
    const float* __restrict__ bias,
    float* __restrict__ Y, int ldy,
    int M, int N, int K)
{
  __shared__ float Xs[32][68];
  __shared__ float Ws[32][68];
  int t = threadIdx.x;
  int tx = t & 15, ty = t >> 4;
  int m0 = blockIdx.y * 64, n0 = blockIdx.x * 64;
  float acc[4][4] = {};
  for (int k0 = 0; k0 < K; k0 += 32) {
#pragma unroll
    for (int q = 0; q < 2; ++q) {
      int idx = t + q * 256;
      int r = idx >> 3, c = (idx & 7) << 2;
      float4 v = *(const float4*)(X + (size_t)(m0 + r) * ldx + k0 + c);
      Xs[c + 0][r] = v.x; Xs[c + 1][r] = v.y; Xs[c + 2][r] = v.z; Xs[c + 3][r] = v.w;
      float4 w = *(const float4*)(W + (size_t)(n0 + r) * K + k0 + c);
      Ws[c + 0][r] = w.x; Ws[c + 1][r] = w.y; Ws[c + 2][r] = w.z; Ws[c + 3][r] = w.w;
    }
    __syncthreads();
#pragma unroll
    for (int kk = 0; kk < 32; ++kk) {
      float a[4], b[4];
#pragma unroll
      for (int u = 0; u < 4; ++u) a[u] = Xs[kk][ty * 4 + u];
#pragma unroll
      for (int u = 0; u < 4; ++u) b[u] = Ws[kk][tx * 4 + u];
#pragma unroll
      for (int i = 0; i < 4; ++i)
#pragma unroll
        for (int j = 0; j < 4; ++j) acc[i][j] += a[i] * b[j];
    }
    __syncthreads();
  }
#pragma unroll
  for (int i = 0; i < 4; ++i) {
    int m = m0 + ty * 4 + i;
#pragma unroll
    for (int j = 0; j < 4; ++j) {
      int n = n0 + tx * 4 + j;
      Y[(size_t)m * ldy + n] = acc[i][j] + bias[n];
    }
  }
}

// ---------------------------------------------------------------------------
// attn_src[b,h,s], attn_dst[b,h,s]
// ---------------------------------------------------------------------------
__global__ __launch_bounds__(192) void k_attnvec(
    const float* __restrict__ feat, const float* __restrict__ w1,
    const float* __restrict__ w2, float* __restrict__ src, float* __restrict__ dst)
{
  int bs = blockIdx.x;
  int t = threadIdx.x;
  int h = t >> 4, l = t & 15;
  float4 f = *(const float4*)(feat + (size_t)bs * DD + h * HDIM + l * 4);
  float4 a = *(const float4*)(w1 + h * HDIM + l * 4);
  float4 c = *(const float4*)(w2 + h * HDIM + l * 4);
  float ps = f.x * a.x + f.y * a.y + f.z * a.z + f.w * a.w;
  float pd = f.x * c.x + f.y * c.y + f.z * c.z + f.w * c.w;
#pragma unroll
  for (int o = 8; o > 0; o >>= 1) {
    ps += __shfl_xor(ps, o);
    pd += __shfl_xor(pd, o);
  }
  if (l == 0) {
    int b = bs >> 9, s = bs & 511;
    src[((b * HH + h) << 9) + s] = ps;
    dst[((b * HH + h) << 9) + s] = pd;
  }
}

// ---------------------------------------------------------------------------
// MFMA fused edge-MLP -> attention scores. One block per (b,i); 4 j-chunks of
// 128, double-buffered LDS + register prefetch (T14). Weights in registers.
// 256 threads = 4 waves; wave w owns j-rows [w*32, w*32+32) of each chunk.
// scores layout: [b][i][h][j]
// ---------------------------------------------------------------------------
__global__ __launch_bounds__(256, 2) void k_scores_mfma(
    const float* __restrict__ wprob, const float* __restrict__ sloop,
    const float* __restrict__ We1, const float* __restrict__ be1,
    const float* __restrict__ We2, const float* __restrict__ be2,
    const float* __restrict__ src, const float* __restrict__ dst,
    float* __restrict__ scores)
{
  __shared__ unsigned short wps_s[2][128][72];   // [buf][j][e] bf16, 36.9 KB
  __shared__ unsigned short hmid_s[128][132];    // [j][f] bf16,   33.8 KB
  __shared__ float masks[128];

  const int blk = blockIdx.x;        // b*512 + i
  const int i = blk & 511;
  const int b = blk >> 9;
  const int t = threadIdx.x;
  const int w = t >> 6, l = t & 63;
  const int lr = l & 15, lg = l >> 4;
  const int jbase = w * 32;

  // zero wps_s (covers pad columns 50..71 for all chunks; staging writes e<50)
  for (int q = t; q < 9216; q += 256) ((unsigned int*)wps_s)[q] = 0u;

  // ---- weight fragments to registers (block-invariant) ----
  s16x8 wa[2][8];   // We1 B-frags [ks][n]: f = n*16+lr, e = ks*32+lg*8+u
#pragma unroll
  for (int ks = 0; ks < 2; ++ks)
#pragma unroll
    for (int n = 0; n < 8; ++n)
#pragma unroll
      for (int u = 0; u < 8; ++u) {
        int e = ks * 32 + lg * 8 + u;
        float v = (e < 50) ? We1[(n * 16 + lr) * 50 + e] : 0.0f;
        wa[ks][n][u] = (short)f2bf(v);
      }
  s16x8 wb[4];      // We2 B-frags [kk]: h = lr, f = kk*32+lg*8+u
#pragma unroll
  for (int kk = 0; kk < 4; ++kk)
#pragma unroll
    for (int u = 0; u < 8; ++u) {
      int f = kk * 32 + lg * 8 + u;
      wb[kk][u] = (short)((lr < 12) ? f2bf(We2[lr * 128 + f]) : (unsigned short)0);
    }
  float be1v[8];
#pragma unroll
  for (int n = 0; n < 8; ++n) be1v[n] = be1[n * 16 + lr];
  const int hc = (lr < 12) ? lr : 0;
  const float be2v = be2[hc];
  const float srcv = src[((b * HH + hc) << 9) + i];
  const float* drow = dst + ((size_t)(b * HH + hc) << 9);

  const size_t rowbase = (size_t)(b * SS + i) * SS * EE;  // floats

  float4 pw[7], psl[7];

#define STAGE_LOAD(cc)                                                       \
  {                                                                          \
    const float* wp = wprob + rowbase + (size_t)(cc) * 6400;                 \
    const float* sl = sloop + rowbase + (size_t)(cc) * 6400;                 \
    _Pragma("unroll")                                                        \
    for (int k = 0; k < 7; ++k)                                              \
      if (k < 6 || t < 64) {                                                 \
        pw[k] = *(const float4*)(wp + 4 * (t + 256 * k));                    \
        psl[k] = *(const float4*)(sl + 4 * (t + 256 * k));                   \
      }                                                                      \
  }

#define STAGE_WRITE(bufw)                                                    \
  {                                                                          \
    _Pragma("unroll")                                                        \
    for (int k = 0; k < 7; ++k)                                              \
      if (k < 6 || t < 64) {                                                 \
        int f = 4 * (t + 256 * k);                                           \
        int j = f / 50;                                                      \
        int e0 = f - j * 50;                                                 \
        float vs[4] = {pw[k].x + psl[k].x, pw[k].y + psl[k].y,               \
                       pw[k].z + psl[k].z, pw[k].w + psl[k].w};              \
        _Pragma("unroll")                                                    \
        for (int u = 0; u < 4; ++u) {                                        \
          int e = e0 + u, jj = j;                                            \
          if (e >= 50) { e -= 50; jj += 1; }                                 \
          wps_s[bufw][jj][e] = f2bf(vs[u]);                                  \
        }                                                                    \
      }                                                                      \
  }

  // prologue: stage chunk 0
  STAGE_LOAD(0);
  STAGE_WRITE(0);
  __syncthreads();

  for (int c = 0; c < 4; ++c) {
    const int buf = c & 1;
    const int j0c = c << 7;

    // dst values for this chunk (issued FIRST so their wait doesn't drain
    // the prefetch queue)
    float4 dv0 = *(const float4*)(drow + j0c + jbase + lg * 4);
    float4 dv1 = *(const float4*)(drow + j0c + jbase + 16 + lg * 4);

    if (c < 3) STAGE_LOAD(c + 1);

    // per-wave masks for own j-rows
    if (l < 32) {
      const unsigned short* row = wps_s[buf][jbase + l];
      float s = 0.0f;
#pragma unroll
      for (int q = 0; q < 6; ++q) {
        s16x8 v = *(const s16x8*)(row + q * 8);
#pragma unroll
        for (int u = 0; u < 8; ++u) s += bf2f((unsigned short)v[u]);
      }
      unsigned int last = *(const unsigned int*)(row + 48);
      s += bf2f((unsigned short)(last & 0xffffu)) + bf2f((unsigned short)(last >> 16));
      masks[jbase + l] = (s == 0.0f) ? 1.0f : 0.0f;
    }

    // ---- stage A: hmid = relu(wps @ We1^T + be1) ----
    f32x4 accA[2][8] = {};
#pragma unroll
    for (int ks = 0; ks < 2; ++ks) {
      s16x8 a0 = *(const s16x8*)&wps_s[buf][jbase + lr][ks * 32 + lg * 8];
      s16x8 a1 = *(const s16x8*)&wps_s[buf][jbase + 16 + lr][ks * 32 + lg * 8];
#pragma unroll
      for (int n = 0; n < 8; ++n) {
        accA[0][n] = __builtin_amdgcn_mfma_f32_16x16x32_bf16(a0, wa[ks][n], accA[0][n], 0, 0, 0);
        accA[1][n] = __builtin_amdgcn_mfma_f32_16x16x32_bf16(a1, wa[ks][n], accA[1][n], 0, 0, 0);
      }
    }
#pragma unroll
    for (int jt = 0; jt < 2; ++jt)
#pragma unroll
      for (int n = 0; n < 8; ++n)
#pragma unroll
        for (int r = 0; r < 4; ++r) {
          float v = fmaxf(accA[jt][n][r] + be1v[n], 0.0f);
          hmid_s[jbase + jt * 16 + lg * 4 + r][n * 16 + lr] = f2bf(v);
        }

    // ---- stage B: A = hmid @ We2^T (wave-local rows) ----
    f32x4 accB[2] = {};
#pragma unroll
    for (int kk = 0; kk < 4; ++kk) {
      s16x8 a0 = *(const s16x8*)&hmid_s[jbase + lr][kk * 32 + lg * 8];
      s16x8 a1 = *(const s16x8*)&hmid_s[jbase + 16 + lr][kk * 32 + lg * 8];
      accB[0] = __builtin_amdgcn_mfma_f32_16x16x32_bf16(a0, wb[kk], accB[0], 0, 0, 0);
      accB[1] = __builtin_amdgcn_mfma_f32_16x16x32_bf16(a1, wb[kk], accB[1], 0, 0, 0);
    }

    // ---- epilogue: leaky-relu + mask, direct float4 stores ----
    if (lr < 12) {
#pragma unroll
      for (int jt = 0; jt < 2; ++jt) {
        int jl = jbase + jt * 16 + lg * 4;   // local j of r=0 (4-aligned)
        const float4 dv = jt ? dv1 : dv0;
        float4 st;
#pragma unroll
        for (int r = 0; r < 4; ++r) {
          float x = accB[jt][r] + be2v + srcv + (&dv.x)[r];
          x = (x > 0.0f) ? x : 0.01f * x;
          if (masks[jl + r] != 0.0f) x = -INFINITY;
          (&st.x)[r] = x;
        }
        *(float4*)(scores + ((((size_t)(b * SS + i)) * HH + lr) << 9) + j0c + jl) = st;
      }
    }

    if (c < 3) {
      STAGE_WRITE(buf ^ 1);
      __syncthreads();
    }
  }
#undef STAGE_LOAD
#undef STAGE_WRITE
}

// ---------------------------------------------------------------------------
// Softmax over j (per b,i,h) + PV: gcnmid[b,i,:] = sum_j attn * feature[b,j,:]
// ---------------------------------------------------------------------------
__global__ __launch_bounds__(256) void k_softmax_pv(
    const float* __restrict__ scores, const float* __restrict__ feat,
    float* __restrict__ gout)
{
  __shared__ float p[2][12][512];
  int blk = blockIdx.x;
  int b = blk >> 8;
  int i0 = (blk & 255) << 1;
  int t = threadIdx.x;
  size_t base = ((size_t)(b * SS + i0) * HH) << 9;
  for (int q = t; q < 12288; q += 256) ((float*)p)[q] = scores[base + q];
  __syncthreads();

  int w = t >> 6, l = t & 63;
  for (int r = w; r < 24; r += 4) {
    int ii = r / 12, h = r % 12;
    float* row = p[ii][h];
    float vv[8];
    float m = -INFINITY;
#pragma unroll
    for (int u = 0; u < 8; ++u) {
      vv[u] = row[l + (u << 6)];
      m = fmaxf(m, vv[u]);
    }
#pragma unroll
    for (int o = 32; o > 0; o >>= 1) m = fmaxf(m, __shfl_xor(m, o));
    float s = 0.0f;
#pragma unroll
    for (int u = 0; u < 8; ++u) {
      float e = __expf(vv[u] - m);
      vv[u] = e;
      s += e;
    }
#pragma unroll
    for (int o = 32; o > 0; o >>= 1) s += __shfl_xor(s, o);
    float inv = 1.0f / s;
#pragma unroll
    for (int u = 0; u < 8; ++u) row[l + (u << 6)] = vv[u] * inv;
  }
  __syncthreads();

  float acc[2][3] = {};
  const float* fb = feat + (size_t)b * SS * DD;
  int h0 = t >> 6;
#pragma unroll 4
  for (int j = 0; j < 512; ++j) {
    const float* fr = fb + (size_t)j * DD;
    float f0 = fr[t], f1 = fr[t + 256], f2 = fr[t + 512];
    float p00 = p[0][h0][j], p10 = p[1][h0][j];
    float p01 = p[0][h0 + 4][j], p11 = p[1][h0 + 4][j];
    float p02 = p[0][h0 + 8][j], p12 = p[1][h0 + 8][j];
    acc[0][0] += p00 * f0; acc[0][1] += p01 * f1; acc[0][2] += p02 * f2;
    acc[1][0] += p10 * f0; acc[1][1] += p11 * f1; acc[1][2] += p12 * f2;
  }
#pragma unroll
  for (int ii = 0; ii < 2; ++ii)
#pragma unroll
    for (int u = 0; u < 3; ++u)
      gout[(size_t)(b * SS + i0 + ii) * DD + t + (u << 8)] = acc[ii][u];
}

// ---------------------------------------------------------------------------
// LayerNorm (torch variant: unbiased std, /(std+eps)) + ReLU -> node (d_out)
// ---------------------------------------------------------------------------
__global__ __launch_bounds__(256) void k_ln(
    const float* __restrict__ gcn2, const float* __restrict__ ga,
    const float* __restrict__ gb, float* __restrict__ out)
{
  __shared__ float rs[4], rss[4];
  int row = blockIdx.x;
  int t = threadIdx.x;
  const float* x = gcn2 + (size_t)row * DD;
  float v[3];
  float s = 0.0f, ss2 = 0.0f;
#pragma unroll
  for (int u = 0; u < 3; ++u) {
    v[u] = x[t + (u << 8)];
    s += v[u];
    ss2 += v[u] * v[u];
  }
#pragma unroll
  for (int o = 32; o > 0; o >>= 1) {
    s += __shfl_down(s, o);
    ss2 += __shfl_down(ss2, o);
  }
  int w = t >> 6, l = t & 63;
  if (l == 0) { rs[w] = s; rss[w] = ss2; }
  __syncthreads();
  float S = rs[0] + rs[1] + rs[2] + rs[3];
  float SSum = rss[0] + rss[1] + rss[2] + rss[3];
  float mean = S * (1.0f / 768.0f);
  float var = (SSum - 768.0f * mean * mean) * (1.0f / 767.0f);
  var = fmaxf(var, 0.0f);
  float rinv = 1.0f / (sqrtf(var) + 1e-6f);
#pragma unroll
  for (int u = 0; u < 3; ++u) {
    int cidx = t + (u << 8);
    float y = ga[cidx] * (v[u] - mean) * rinv + gb[cidx];
    out[(size_t)row * DD + cidx] = fmaxf(y, 0.0f);
  }
}

// ---------------------------------------------------------------------------
// P[b,s,f] = ediag[b,s]@Wh_ei^T + node[b,s]@Wh_n2^T
// Q[b,s,f] = ediag[b,s]@Wh_ej^T + node[b,s]@Wh_n1^T + bh
// ---------------------------------------------------------------------------
__global__ __launch_bounds__(256) void k_pq(
    const float* __restrict__ node, const float* __restrict__ wadj,
    const float* __restrict__ Whei, const float* __restrict__ Whej,
    const float* __restrict__ Whn1, const float* __restrict__ Whn2,
    const float* __restrict__ bh, float* __restrict__ P, float* __restrict__ Q)
{
  __shared__ float nd[768];
  __shared__ float ed[50];
  int bs = blockIdx.x;
  int b = bs >> 9, s = bs & 511;
  int t = threadIdx.x;
  for (int q = t; q < 768; q += 256) nd[q] = node[(size_t)bs * DD + q];
  if (t < 50) ed[t] = wadj[((size_t)(b * SS + s) * SS + s) * EE + t];
  __syncthreads();
  int which = t >> 7, f = t & 127;
  if (f < 50) {
    const float* We = which ? Whej : Whei;
    const float* Wn = which ? Whn1 : Whn2;
    float acc = which ? bh[f] : 0.0f;
    for (int e = 0; e < 50; ++e) acc += ed[e] * We[f * EE + e];
    for (int d = 0; d < 768; ++d) acc += nd[d] * Wn[f * DD + d];
    (which ? Q : P)[(size_t)bs * DE + f] = acc;
  }
}

// ---------------------------------------------------------------------------
// edge_out[n,f] = wadj[n,:]@Wh_e[f,:] + P[b,i,f] + Q[b,j,f]
// ---------------------------------------------------------------------------
__global__ __launch_bounds__(256) void k_edge(
    const float* __restrict__ wadj, const float* __restrict__ Whe,
    const float* __restrict__ P, const float* __restrict__ Q,
    float* __restrict__ eout)
{
  __shared__ float adjs[128][51];
  __shared__ float whes[52][52];
  int t = threadIdx.x;
  size_t n0 = (size_t)blockIdx.x * 128;
  for (int q = t; q < 2500; q += 256) whes[q / 50][q % 50] = Whe[q];
  for (int q = t; q < 52 * 52 - 2600; q += 256) {
    int qq = q + 2600;
    whes[qq / 52][qq % 52] = 0.0f;
  }
  for (int q = t; q < 6400; q += 256) adjs[q / 50][q % 50] = wadj[n0 * EE + q];
  __syncthreads();

  int pl = t & 31;
  int fg = t >> 5;
  int f0 = fg < 2 ? fg * 7 : 14 + (fg - 2) * 6;
  int nf = fg < 2 ? 7 : 6;
  float acc[4][7] = {};
  for (int e = 0; e < 50; ++e) {
    float aw[7];
#pragma unroll
    for (int u = 0; u < 7; ++u) aw[u] = whes[f0 + u][e];
    float ap0 = adjs[pl][e], ap1 = adjs[pl + 32][e];
    float ap2 = adjs[pl + 64][e], ap3 = adjs[pl + 96][e];
#pragma unroll
    for (int u = 0; u < 7; ++u) {
      acc[0][u] += ap0 * aw[u];
      acc[1][u] += ap1 * aw[u];
      acc[2][u] += ap2 * aw[u];
      acc[3][u] += ap3 * aw[u];
    }
  }
#pragma unroll
  for (int pp = 0; pp < 4; ++pp) {
    size_t n = n0 + pl + 32 * pp;
    int b = (int)(n >> 18);
    int rem = (int)(n & 262143);
    int i = rem >> 9, j = rem & 511;
    const float* Pr = P + (size_t)(b * SS + i) * DE;
    const float* Qr = Q + (size_t)(b * SS + j) * DE;
    float* orow = eout + n * DE;
    for (int u = 0; u < nf; ++u) {
      int f = f0 + u;
      orow[f] = acc[pp][u] + Pr[f] + Qr[f];
    }
  }
}

// ---------------------------------------------------------------------------
extern "C" void kernel_launch(void* const* d_in, const int* in_sizes, int n_in,
                              void* d_out, int out_size, void* d_ws, size_t ws_size,
                              hipStream_t stream)
{
  const float* wprob = (const float*)d_in[0];
  const float* wadj  = (const float*)d_in[1];
  const float* gin   = (const float*)d_in[2];
  const float* sloop = (const float*)d_in[3];
  const float* W_lin = (const float*)d_in[4];
  const float* b_lin = (const float*)d_in[5];
  const float* fw1   = (const float*)d_in[6];
  const float* fw2   = (const float*)d_in[7];
  const float* We1   = (const float*)d_in[8];
  const float* be1   = (const float*)d_in[9];
  const float* We2   = (const float*)d_in[10];
  const float* be2   = (const float*)d_in[11];
  const float* W_out = (const float*)d_in[12];
  const float* b_out = (const float*)d_in[13];
  const float* ln_a  = (const float*)d_in[14];
  const float* ln_b  = (const float*)d_in[15];
  const float* Whe   = (const float*)d_in[16];
  const float* Whei  = (const float*)d_in[17];
  const float* Whej  = (const float*)d_in[18];
  const float* Whn1  = (const float*)d_in[19];
  const float* Whn2  = (const float*)d_in[20];
  const float* bh    = (const float*)d_in[21];

  float* ws = (float*)d_ws;
  float* feature = ws + 0;         // [B,S,D]      786432
  float* src     = ws + 786432;    // [B,H,S]      12288
  float* dst     = ws + 798720;    // [B,H,S]      12288
  float* scores  = ws + 811008;    // [B,S,H,S]    6291456
  float* gcnmid  = ws + 7102464;   // [B,S,D]      786432
  float* gcn2    = ws + 7888896;   // [B,S,D]      786432
  float* P       = ws + 8675328;   // [B,S,DE]     51200
  float* Q       = ws + 8726528;   // [B,S,DE]     51200

  float* node = (float*)d_out;            // output 0: [B,S,D]
  float* eout = (float*)d_out + 786432;   // output 1: [B,S,S,DE]

  k_gemm_bias<<<dim3(DD / 64, (BB * SS) / 64), 256, 0, stream>>>(
      gin, DD, W_lin, b_lin, feature, DD, BB * SS, DD, DD);
  k_attnvec<<<BB * SS, 192, 0, stream>>>(feature, fw1, fw2, src, dst);
  k_scores_mfma<<<BB * SS, 256, 0, stream>>>(
      wprob, sloop, We1, be1, We2, be2, src, dst, scores);
  k_softmax_pv<<<BB * SS / 2, 256, 0, stream>>>(scores, feature, gcnmid);
  k_gemm_bias<<<dim3(DD / 64, (BB * SS) / 64), 256, 0, stream>>>(
      gcnmid, DD, W_out, b_out, gcn2, DD, BB * SS, DD, DD);
  k_ln<<<BB * SS, 256, 0, stream>>>(gcn2, ln_a, ln_b, node);
  k_pq<<<BB * SS, 256, 0, stream>>>(node, wadj, Whei, Whej, Whn1, Whn2, bh, P, Q);
  k_edge<<<(BB * SS * SS) / 128, 256, 0, stream>>>(wadj, Whe, P, Q, eout);
}